// Round 10
// baseline (6988.712 us; speedup 1.0000x reference)
//
#include <hip/hip_runtime.h>
#include <hip/hip_bf16.h>
#include <math.h>

#define VOCAB 50257
#define NCLS 20
#define EDIM 64
#define HDIM 64
#define BATCH 128
#define TLEN 2048

typedef float v2f __attribute__((ext_vector_type(2)));

// Static device scratch: no dependence on ws_size, graph-capture safe.
__device__ float g_P[(size_t)2 * VOCAB * 192];   // 77.2 MB, input-projected vocab table (bias folded)
__device__ float g_feats[BATCH * 256];           // pooled features
__device__ float g_probe[2 * BATCH * 64];        // probe sink (never read by outputs)

__device__ __forceinline__ float fast_rcp(float x) { return __builtin_amdgcn_rcpf(x); }

__device__ __forceinline__ float fsigmoid(float x) {
    return fast_rcp(1.f + __expf(-x));
}
__device__ __forceinline__ float ftanh(float x) {
    float e = __expf(2.f * x);
    return 1.f - 2.f * fast_rcp(e + 1.f);
}

// ======================= DIAGNOSTIC PROBES (round 9: readable encoding) =======================
// Channel limits: top-5 table shows only the slowest kernel; dur_us gives the sum.
// => probe_fullmath runs 8 reps (direct read: slowest kernel in table, value = FM8/8);
//    probe_gather runs 2 reps (derived: (dur_us - FM8 - ~950us base)/2).

#define PROBE_WINIT(SRC)                                                        \
    v2f w0, w1, w2, w3, w4, w5, w6, w7;                                         \
    {                                                                           \
        const float4* p_ = (const float4*)((SRC) + (size_t)lane * 64);          \
        float4 q0 = p_[0]; w0 = (v2f){q0.x, q0.y}; w1 = (v2f){q0.z, q0.w};      \
        float4 q1 = p_[1]; w2 = (v2f){q1.x, q1.y}; w3 = (v2f){q1.z, q1.w};      \
        float4 q2 = p_[2]; w4 = (v2f){q2.x, q2.y}; w5 = (v2f){q2.z, q2.w};      \
        float4 q3 = p_[3]; w6 = (v2f){q3.x, q3.y}; w7 = (v2f){q3.z, q3.w};      \
    }

#define PROBE_DOT6(H01, H23)                                                    \
        ar0 = __builtin_elementwise_fma(H01, w0, ar0);                          \
        az0 = __builtin_elementwise_fma(H01, w2, az0);                          \
        an0 = __builtin_elementwise_fma(H01, w4, an0);                          \
        ar1 = __builtin_elementwise_fma(H23, w1, ar1);                          \
        az1 = __builtin_elementwise_fma(H23, w3, az1);                          \
        an1 = __builtin_elementwise_fma(H23, w5, an1);

// dot (96 v2f FMA) + 16 b128 LDS broadcast reads + exact sigmoid/tanh tail.
// Mirrors the real step minus the P-gather. reps x 2048 steps.
__global__ __launch_bounds__(64, 1) void probe_fullmath(const float* __restrict__ whh,
                                                        const float* __restrict__ bhh,
                                                        int reps) {
    const int lane = threadIdx.x;
    PROBE_WINIT(whh)
    const float br = bhh[lane], bz = bhh[64 + lane], bn = bhh[128 + lane];
    __shared__ __align__(16) float h_lds[64];
    float h = 0.f, sum = 0.f, mx = -INFINITY;
    h_lds[lane] = h;
    for (int rep = 0; rep < reps; rep++) {
#pragma unroll 4
        for (int s = 0; s < TLEN; s++) {
            v2f ar0 = {0,0}, ar1 = {0,0}, az0 = {0,0}, az1 = {0,0}, an0 = {0,0}, an1 = {0,0};
#pragma unroll
            for (int k = 0; k < 8; k++) {
                float4 ha = *(const float4*)(h_lds + 8 * k);
                float4 hb = *(const float4*)(h_lds + 8 * k + 4);
                v2f a01 = {ha.x, ha.y}, a23 = {ha.z, ha.w};
                v2f b01 = {hb.x, hb.y}, b23 = {hb.z, hb.w};
                PROBE_DOT6(a01, a23)
                ar0 = __builtin_elementwise_fma(b01, w6, ar0);
                az0 = __builtin_elementwise_fma(b01, w0, az0);
                an0 = __builtin_elementwise_fma(b01, w2, an0);
                ar1 = __builtin_elementwise_fma(b23, w7, ar1);
                az1 = __builtin_elementwise_fma(b23, w1, az1);
                an1 = __builtin_elementwise_fma(b23, w3, an1);
            }
            float hr = (ar0.x + ar0.y) + (ar1.x + ar1.y);
            float hz = (az0.x + az0.y) + (az1.x + az1.y);
            float hn = (an0.x + an0.y) + (an1.x + an1.y);
            float r = fsigmoid(0.1f + hr + br);
            float z = fsigmoid(-0.2f + hz + bz);
            float n = ftanh(0.3f + r * (hn + bn));
            h = fmaf(z, h - n, n);
            sum += h; mx = fmaxf(mx, h);
            h_lds[lane] = h;                       // single wave: in-order LDS, no barrier
        }
    }
    g_probe[blockIdx.x * 64 + lane] = sum + mx + h;
}

// ONLY the token->P asm ring with tied vmcnt + sink FMA. reps x 2048 steps.
__global__ __launch_bounds__(64, 1) void probe_gather(const int* __restrict__ tokens,
                                                      int reps) {
    const int lane = threadIdx.x;
    const int blk = blockIdx.x;
    const int b = blk >> 1;
    const int dir = blk & 1;
    const float* Pd = g_P + (size_t)dir * VOCAB * 192;
    __shared__ __align__(16) int tok_lds[TLEN];
    {
        const int4* src = (const int4*)(tokens + (size_t)b * TLEN);
        int4* dst = (int4*)tok_lds;
        for (int t = lane; t < TLEN / 4; t += 64) dst[t] = src[t];
    }
    auto tok_at = [&](int s) -> int {
        int ss = s < TLEN ? s : TLEN - 1;
        return tok_lds[dir ? (TLEN - 1 - ss) : ss];
    };
    float acc = 0.f;
    for (int rep = 0; rep < reps; rep++) {
        float xr0, xz0, xn0, xr1, xz1, xn1, xr2, xz2, xn2, xr3, xz3, xn3;
#define PG_PRE(SL, D) do {                                                             \
        const float* rd_ = Pd + (size_t)tok_at(D) * 192;                               \
        asm volatile("global_load_dword %0, %1, off" : "=v"(xr##SL) : "v"(rd_ + lane));       \
        asm volatile("global_load_dword %0, %1, off" : "=v"(xz##SL) : "v"(rd_ + 64 + lane));  \
        asm volatile("global_load_dword %0, %1, off" : "=v"(xn##SL) : "v"(rd_ + 128 + lane)); \
    } while (0)
        PG_PRE(0, 0); PG_PRE(1, 1); PG_PRE(2, 2); PG_PRE(3, 3);
#define PG_STEP(SL, SB) do {                                                           \
        const int tN_ = tok_at((SB) + 4);                                              \
        asm volatile("s_waitcnt vmcnt(9)" : "+v"(xr##SL), "+v"(xz##SL), "+v"(xn##SL)); \
        acc = fmaf(xr##SL, 1e-7f, acc);                                                \
        acc = fmaf(xz##SL, 1e-7f, acc);                                                \
        acc = fmaf(xn##SL, 1e-7f, acc);                                                \
        const float* rp_ = Pd + (size_t)tN_ * 192;                                     \
        asm volatile("global_load_dword %0, %1, off" : "=v"(xr##SL) : "v"(rp_ + lane));       \
        asm volatile("global_load_dword %0, %1, off" : "=v"(xz##SL) : "v"(rp_ + 64 + lane));  \
        asm volatile("global_load_dword %0, %1, off" : "=v"(xn##SL) : "v"(rp_ + 128 + lane)); \
    } while (0)
        for (int s = 0; s < TLEN; s += 4) {
            PG_STEP(0, s + 0); PG_STEP(1, s + 1); PG_STEP(2, s + 2); PG_STEP(3, s + 3);
        }
        asm volatile("s_waitcnt vmcnt(0)" ::: "memory");
#undef PG_PRE
#undef PG_STEP
    }
    g_probe[blockIdx.x * 64 + lane] = acc;
}

// ===================== REAL PIPELINE (round-4 verbatim, best: gru 818-822us) =====================

__global__ __launch_bounds__(384) void precompute_P(
    const float* __restrict__ emb,
    const float* __restrict__ wih_f, const float* __restrict__ bih_f,
    const float* __restrict__ wih_b, const float* __restrict__ bih_b)
{
    const int t = threadIdx.x;
    const int dir = t / 192;
    const int g = t % 192;
    const float* wih = dir ? wih_b : wih_f;
    const float* bih = dir ? bih_b : bih_f;

    float w[64];
#pragma unroll
    for (int e = 0; e < 64; e += 4) {
        float4 v = *(const float4*)(wih + (size_t)g * 64 + e);
        w[e] = v.x; w[e + 1] = v.y; w[e + 2] = v.z; w[e + 3] = v.w;
    }
    const float bias = bih[g];
    float* Pd = g_P + (size_t)dir * VOCAB * 192;

    for (int v = blockIdx.x * 2; v < VOCAB; v += gridDim.x * 2) {
        const int v1ok = (v + 1 < VOCAB);
        const float4* e0 = (const float4*)(emb + (size_t)v * 64);
        const float4* e1 = (const float4*)(emb + (size_t)(v1ok ? v + 1 : v) * 64);
        float a0 = bias, a1 = bias;
#pragma unroll
        for (int e4 = 0; e4 < 16; e4++) {
            float4 x = e0[e4];
            float4 y = e1[e4];
            a0 = fmaf(x.x, w[4 * e4 + 0], a0);
            a1 = fmaf(y.x, w[4 * e4 + 0], a1);
            a0 = fmaf(x.y, w[4 * e4 + 1], a0);
            a1 = fmaf(y.y, w[4 * e4 + 1], a1);
            a0 = fmaf(x.z, w[4 * e4 + 2], a0);
            a1 = fmaf(y.z, w[4 * e4 + 2], a1);
            a0 = fmaf(x.w, w[4 * e4 + 3], a0);
            a1 = fmaf(y.w, w[4 * e4 + 3], a1);
        }
        Pd[(size_t)v * 192 + g] = a0;
        if (v1ok) Pd[(size_t)(v + 1) * 192 + g] = a1;
    }
}

__global__ __launch_bounds__(64, 1) __attribute__((amdgpu_waves_per_eu(1, 1)))
void gru_seq(
    const int* __restrict__ tokens,
    const float* __restrict__ whh_f, const float* __restrict__ bhh_f,
    const float* __restrict__ whh_b, const float* __restrict__ bhh_b)
{
    const int lane = threadIdx.x;
    const int blk = blockIdx.x;
    const int b = blk >> 1;
    const int dir = blk & 1;
    const float* whh = dir ? whh_b : whh_f;
    const float* bhh = dir ? bhh_b : bhh_f;
    const float* Pd = g_P + (size_t)dir * VOCAB * 192;

    __shared__ __align__(16) float h_lds[64];
    __shared__ __align__(16) int tok_lds[TLEN];

    {
        const int4* src = (const int4*)(tokens + (size_t)b * TLEN);
        int4* dst = (int4*)tok_lds;
        for (int t = lane; t < TLEN / 4; t += 64) dst[t] = src[t];
    }

    v2f wr[32], wz[32], wn[32];
    {
        const float* pr = whh + (size_t)(0 + lane) * 64;
        const float* pz = whh + (size_t)(64 + lane) * 64;
        const float* pn = whh + (size_t)(128 + lane) * 64;
#pragma unroll
        for (int k = 0; k < 16; k++) {
            float4 a = *(const float4*)(pr + 4 * k);
            wr[2 * k] = (v2f){a.x, a.y}; wr[2 * k + 1] = (v2f){a.z, a.w};
            float4 c = *(const float4*)(pz + 4 * k);
            wz[2 * k] = (v2f){c.x, c.y}; wz[2 * k + 1] = (v2f){c.z, c.w};
            float4 d = *(const float4*)(pn + 4 * k);
            wn[2 * k] = (v2f){d.x, d.y}; wn[2 * k + 1] = (v2f){d.z, d.w};
        }
    }
    const float br = bhh[lane], bz = bhh[64 + lane], bn = bhh[128 + lane];

    h_lds[lane] = 0.f;
    float h = 0.f, sum = 0.f, mx = -INFINITY;

    auto tok_at = [&](int s) -> int {
        int ss = s < TLEN ? s : TLEN - 1;
        return tok_lds[dir ? (TLEN - 1 - ss) : ss];
    };

    float xr0, xz0, xn0, xr1, xz1, xn1, xr2, xz2, xn2, xr3, xz3, xn3;

#define GRU_PRE(SL, D) do {                                                        \
        const float* rd_ = Pd + (size_t)tok_at(D) * 192;                           \
        asm volatile("global_load_dword %0, %1, off" : "=v"(xr##SL) : "v"(rd_ + lane));       \
        asm volatile("global_load_dword %0, %1, off" : "=v"(xz##SL) : "v"(rd_ + 64 + lane));  \
        asm volatile("global_load_dword %0, %1, off" : "=v"(xn##SL) : "v"(rd_ + 128 + lane)); \
    } while (0)

    GRU_PRE(0, 0); GRU_PRE(1, 1); GRU_PRE(2, 2); GRU_PRE(3, 3);

#define GRU_STEP(SL, SB) do {                                                      \
        const int tN_ = tok_at((SB) + 4);                                          \
        v2f ar0 = {0.f, 0.f}, ar1 = {0.f, 0.f};                                    \
        v2f az0 = {0.f, 0.f}, az1 = {0.f, 0.f};                                    \
        v2f an0 = {0.f, 0.f}, an1 = {0.f, 0.f};                                    \
        _Pragma("unroll")                                                          \
        for (int k = 0; k < 16; k++) {                                             \
            float4 h4 = *(const float4*)(h_lds + 4 * k);                           \
            v2f h01 = {h4.x, h4.y}, h23 = {h4.z, h4.w};                            \
            ar0 = __builtin_elementwise_fma(h01, wr[2 * k], ar0);                  \
            az0 = __builtin_elementwise_fma(h01, wz[2 * k], az0);                  \
            an0 = __builtin_elementwise_fma(h01, wn[2 * k], an0);                  \
            ar1 = __builtin_elementwise_fma(h23, wr[2 * k + 1], ar1);              \
            az1 = __builtin_elementwise_fma(h23, wz[2 * k + 1], az1);              \
            an1 = __builtin_elementwise_fma(h23, wn[2 * k + 1], an1);              \
        }                                                                          \
        float hr = (ar0.x + ar0.y) + (ar1.x + ar1.y);                              \
        float hz = (az0.x + az0.y) + (az1.x + az1.y);                              \
        float hn = (an0.x + an0.y) + (an1.x + an1.y);                              \
        asm volatile("s_waitcnt vmcnt(9)"                                          \
                     : "+v"(xr##SL), "+v"(xz##SL), "+v"(xn##SL));                  \
        float r_ = fsigmoid(xr##SL + hr + br);                                     \
        float z_ = fsigmoid(xz##SL + hz + bz);                                     \
        float n_ = ftanh(xn##SL + r_ * (hn + bn));                                 \
        h = fmaf(z_, h - n_, n_);                                                  \
        sum += h;                                                                  \
        mx = fmaxf(mx, h);                                                         \
        h_lds[lane] = h;                                                           \
        const float* rp_ = Pd + (size_t)tN_ * 192;                                 \
        asm volatile("global_load_dword %0, %1, off" : "=v"(xr##SL) : "v"(rp_ + lane));       \
        asm volatile("global_load_dword %0, %1, off" : "=v"(xz##SL) : "v"(rp_ + 64 + lane));  \
        asm volatile("global_load_dword %0, %1, off" : "=v"(xn##SL) : "v"(rp_ + 128 + lane)); \
    } while (0)

    for (int s = 0; s < TLEN; s += 4) {
        GRU_STEP(0, s + 0);
        GRU_STEP(1, s + 1);
        GRU_STEP(2, s + 2);
        GRU_STEP(3, s + 3);
    }
    asm volatile("s_waitcnt vmcnt(0)" ::: "memory");

    g_feats[b * 256 + dir * 64 + lane] = sum * (1.f / TLEN);
    g_feats[b * 256 + 128 + dir * 64 + lane] = mx;
#undef GRU_PRE
#undef GRU_STEP
}

__global__ __launch_bounds__(64) void classifier(
    const float* __restrict__ w1, const float* __restrict__ b1,
    const float* __restrict__ w2, const float* __restrict__ b2,
    float* __restrict__ out)
{
    const int b = blockIdx.x;
    const int i = threadIdx.x;
    __shared__ float f[256];
    __shared__ float hid[64];
    for (int c = i; c < 256; c += 64) f[c] = g_feats[b * 256 + c];
    __syncthreads();

    float acc = b1[i];
    const float* wrow = w1 + (size_t)i * 256;
#pragma unroll 16
    for (int c = 0; c < 256; c++) acc = fmaf(f[c], wrow[c], acc);
    hid[i] = acc * 0.5f * (1.f + erff(acc * 0.70710678118654752f));
    __syncthreads();

    if (i < NCLS) {
        float o = b2[i];
        const float* w2r = w2 + (size_t)i * 64;
#pragma unroll
        for (int j = 0; j < 64; j++) o = fmaf(hid[j], w2r[j], o);
        out[b * NCLS + i] = o;
    }
}

extern "C" void kernel_launch(void* const* d_in, const int* in_sizes, int n_in,
                              void* d_out, int out_size, void* d_ws, size_t ws_size,
                              hipStream_t stream) {
    const int*   tokens = (const int*)  d_in[0];
    const float* emb    = (const float*)d_in[1];
    const float* wih_f  = (const float*)d_in[2];
    const float* whh_f  = (const float*)d_in[3];
    const float* bih_f  = (const float*)d_in[4];
    const float* bhh_f  = (const float*)d_in[5];
    const float* wih_b  = (const float*)d_in[6];
    const float* whh_b  = (const float*)d_in[7];
    const float* bih_b  = (const float*)d_in[8];
    const float* bhh_b  = (const float*)d_in[9];
    const float* w1     = (const float*)d_in[10];
    const float* b1     = (const float*)d_in[11];
    const float* w2     = (const float*)d_in[12];
    const float* b2     = (const float*)d_in[13];
    float* out = (float*)d_out;

    // probe_fullmath x8: direct read (slowest kernel -> top-5 table). value@2048 = dur/8.
    probe_fullmath<<<256, 64, 0, stream>>>(whh_f, bhh_f, 8);

    // real pipeline (round-4 verbatim)
    precompute_P<<<4096, 384, 0, stream>>>(emb, wih_f, bih_f, wih_b, bih_b);

    // probe_gather x2 (after P filled): derived = (dur_us_total - FM8 - ~950) / 2.
    probe_gather<<<256, 64, 0, stream>>>(tokens, 2);

    gru_seq<<<2 * BATCH, 64, 0, stream>>>(tokens, whh_f, bhh_f, whh_b, bhh_b);
    classifier<<<BATCH, 64, 0, stream>>>(w1, b1, w2, b2, out);
}

// Round 11
// 1151.756 us; speedup vs baseline: 6.0679x; 6.0679x over previous
//
#include <hip/hip_runtime.h>
#include <hip/hip_bf16.h>
#include <math.h>

#define VOCAB 50257
#define NCLS 20
#define EDIM 64
#define HDIM 64
#define BATCH 128
#define TLEN 2048

typedef float v2f __attribute__((ext_vector_type(2)));

// Static device scratch: no dependence on ws_size, graph-capture safe.
__device__ float g_P[(size_t)2 * VOCAB * 192];   // 77.2 MB, input-projected vocab table (bias folded)
__device__ float g_feats[BATCH * 256];           // pooled features

__device__ __forceinline__ float fast_rcp(float x) { return __builtin_amdgcn_rcpf(x); }

__device__ __forceinline__ float fsigmoid(float x) {
    return fast_rcp(1.f + __expf(-x));
}
__device__ __forceinline__ float ftanh(float x) {
    float e = __expf(2.f * x);
    return 1.f - 2.f * fast_rcp(e + 1.f);
}

// ---------------- Kernel A: P[dir][v][g] = dot(emb[v], wih[dir][g]) + bih[dir][g] ----------------
__global__ __launch_bounds__(384) void precompute_P(
    const float* __restrict__ emb,
    const float* __restrict__ wih_f, const float* __restrict__ bih_f,
    const float* __restrict__ wih_b, const float* __restrict__ bih_b)
{
    const int t = threadIdx.x;
    const int dir = t / 192;
    const int g = t % 192;
    const float* wih = dir ? wih_b : wih_f;
    const float* bih = dir ? bih_b : bih_f;

    float w[64];
#pragma unroll
    for (int e = 0; e < 64; e += 4) {
        float4 v = *(const float4*)(wih + (size_t)g * 64 + e);
        w[e] = v.x; w[e + 1] = v.y; w[e + 2] = v.z; w[e + 3] = v.w;
    }
    const float bias = bih[g];
    float* Pd = g_P + (size_t)dir * VOCAB * 192;

    for (int v = blockIdx.x * 2; v < VOCAB; v += gridDim.x * 2) {
        const int v1ok = (v + 1 < VOCAB);
        const float4* e0 = (const float4*)(emb + (size_t)v * 64);
        const float4* e1 = (const float4*)(emb + (size_t)(v1ok ? v + 1 : v) * 64);
        float a0 = bias, a1 = bias;
#pragma unroll
        for (int e4 = 0; e4 < 16; e4++) {
            float4 x = e0[e4];
            float4 y = e1[e4];
            a0 = fmaf(x.x, w[4 * e4 + 0], a0);
            a1 = fmaf(y.x, w[4 * e4 + 0], a1);
            a0 = fmaf(x.y, w[4 * e4 + 1], a0);
            a1 = fmaf(y.y, w[4 * e4 + 1], a1);
            a0 = fmaf(x.z, w[4 * e4 + 2], a0);
            a1 = fmaf(y.z, w[4 * e4 + 2], a1);
            a0 = fmaf(x.w, w[4 * e4 + 3], a0);
            a1 = fmaf(y.w, w[4 * e4 + 3], a1);
        }
        Pd[(size_t)v * 192 + g] = a0;
        if (v1ok) Pd[(size_t)(v + 1) * 192 + g] = a1;
    }
}

// ---------------- Kernel B: one wave per (dir,batch); SGB-clustered LDS reads ----------------
// R10 probe decomposition: fullmath (dot+LDS+gates, NO gather) = 735us of the real 820us;
// gather = ~80us and fully hidden. The wall is the per-step LDS+math serial chain (~860 cyc,
// only ~140 VALU issue). Root cause: source-order k-loop interleaves each ds_read_b128 with
// its 6 FMAs, so read issue serializes behind FMA issue and the last read's ~120cyc latency
// lands ~300+ cyc into the step. Fix (T19): sched_group_barrier(DS_READ,16) pins all 16
// broadcast reads at the top of each step; compiler's fine-grained lgkmcnt lets FMAs start
// as operands arrive. sched_barrier(0) at step end makes each step its own scheduling
// region. Arithmetic order is BIT-IDENTICAL to the verified 822us kernel (absmax 0.0).
__global__ __launch_bounds__(64, 1) __attribute__((amdgpu_waves_per_eu(1, 1)))
void gru_seq(
    const int* __restrict__ tokens,
    const float* __restrict__ whh_f, const float* __restrict__ bhh_f,
    const float* __restrict__ whh_b, const float* __restrict__ bhh_b)
{
    const int lane = threadIdx.x;
    const int blk = blockIdx.x;
    const int b = blk >> 1;
    const int dir = blk & 1;
    const float* whh = dir ? whh_b : whh_f;
    const float* bhh = dir ? bhh_b : bhh_f;
    const float* Pd = g_P + (size_t)dir * VOCAB * 192;

    __shared__ __align__(16) float h_lds[64];
    __shared__ __align__(16) int tok_lds[TLEN];

    {
        const int4* src = (const int4*)(tokens + (size_t)b * TLEN);
        int4* dst = (int4*)tok_lds;
        for (int t = lane; t < TLEN / 4; t += 64) dst[t] = src[t];
    }

    v2f wr[32], wz[32], wn[32];
    {
        const float* pr = whh + (size_t)(0 + lane) * 64;
        const float* pz = whh + (size_t)(64 + lane) * 64;
        const float* pn = whh + (size_t)(128 + lane) * 64;
#pragma unroll
        for (int k = 0; k < 16; k++) {
            float4 a = *(const float4*)(pr + 4 * k);
            wr[2 * k] = (v2f){a.x, a.y}; wr[2 * k + 1] = (v2f){a.z, a.w};
            float4 c = *(const float4*)(pz + 4 * k);
            wz[2 * k] = (v2f){c.x, c.y}; wz[2 * k + 1] = (v2f){c.z, c.w};
            float4 d = *(const float4*)(pn + 4 * k);
            wn[2 * k] = (v2f){d.x, d.y}; wn[2 * k + 1] = (v2f){d.z, d.w};
        }
    }
    const float br = bhh[lane], bz = bhh[64 + lane], bn = bhh[128 + lane];

    h_lds[lane] = 0.f;
    float h = 0.f, sum = 0.f, mx = -INFINITY;

    auto tok_at = [&](int s) -> int {
        int ss = s < TLEN ? s : TLEN - 1;
        return tok_lds[dir ? (TLEN - 1 - ss) : ss];
    };

    float xr0, xz0, xn0, xr1, xz1, xn1, xr2, xz2, xn2, xr3, xz3, xn3;

#define GRU_PRE(SL, D) do {                                                        \
        const float* rd_ = Pd + (size_t)tok_at(D) * 192;                           \
        asm volatile("global_load_dword %0, %1, off" : "=v"(xr##SL) : "v"(rd_ + lane));       \
        asm volatile("global_load_dword %0, %1, off" : "=v"(xz##SL) : "v"(rd_ + 64 + lane));  \
        asm volatile("global_load_dword %0, %1, off" : "=v"(xn##SL) : "v"(rd_ + 128 + lane)); \
    } while (0)

    GRU_PRE(0, 0); GRU_PRE(1, 1); GRU_PRE(2, 2); GRU_PRE(3, 3);

    // one k-slice of the dot; identical FMA/accumulation order to the verified kernel
#define DOTK(K)                                                                    \
        { v2f h01 = {H##K.x, H##K.y}, h23 = {H##K.z, H##K.w};                      \
          ar0 = __builtin_elementwise_fma(h01, wr[2 * K], ar0);                    \
          az0 = __builtin_elementwise_fma(h01, wz[2 * K], az0);                    \
          an0 = __builtin_elementwise_fma(h01, wn[2 * K], an0);                    \
          ar1 = __builtin_elementwise_fma(h23, wr[2 * K + 1], ar1);                \
          az1 = __builtin_elementwise_fma(h23, wz[2 * K + 1], az1);                \
          an1 = __builtin_elementwise_fma(h23, wn[2 * K + 1], an1); }

#define GRU_STEP(SL, SB) do {                                                      \
        /* T19: pin all 16 h-broadcast ds_read_b128 at region start */             \
        __builtin_amdgcn_sched_group_barrier(0x100, 16, 0);                        \
        float4 H0  = *(const float4*)(h_lds + 0);                                  \
        float4 H1  = *(const float4*)(h_lds + 4);                                  \
        float4 H2  = *(const float4*)(h_lds + 8);                                  \
        float4 H3  = *(const float4*)(h_lds + 12);                                 \
        float4 H4  = *(const float4*)(h_lds + 16);                                 \
        float4 H5  = *(const float4*)(h_lds + 20);                                 \
        float4 H6  = *(const float4*)(h_lds + 24);                                 \
        float4 H7  = *(const float4*)(h_lds + 28);                                 \
        float4 H8  = *(const float4*)(h_lds + 32);                                 \
        float4 H9  = *(const float4*)(h_lds + 36);                                 \
        float4 H10 = *(const float4*)(h_lds + 40);                                 \
        float4 H11 = *(const float4*)(h_lds + 44);                                 \
        float4 H12 = *(const float4*)(h_lds + 48);                                 \
        float4 H13 = *(const float4*)(h_lds + 52);                                 \
        float4 H14 = *(const float4*)(h_lds + 56);                                 \
        float4 H15 = *(const float4*)(h_lds + 60);                                 \
        const int tN_ = tok_at((SB) + 4);                                          \
        v2f ar0 = {0.f, 0.f}, ar1 = {0.f, 0.f};                                    \
        v2f az0 = {0.f, 0.f}, az1 = {0.f, 0.f};                                    \
        v2f an0 = {0.f, 0.f}, an1 = {0.f, 0.f};                                    \
        DOTK(0)  DOTK(1)  DOTK(2)  DOTK(3)                                         \
        DOTK(4)  DOTK(5)  DOTK(6)  DOTK(7)                                         \
        DOTK(8)  DOTK(9)  DOTK(10) DOTK(11)                                        \
        DOTK(12) DOTK(13) DOTK(14) DOTK(15)                                        \
        float hr = (ar0.x + ar0.y) + (ar1.x + ar1.y);                              \
        float hz = (az0.x + az0.y) + (az1.x + az1.y);                              \
        float hn = (an0.x + an0.y) + (an1.x + an1.y);                              \
        asm volatile("s_waitcnt vmcnt(9)"                                          \
                     : "+v"(xr##SL), "+v"(xz##SL), "+v"(xn##SL));                  \
        float r_ = fsigmoid(xr##SL + hr + br);                                     \
        float z_ = fsigmoid(xz##SL + hz + bz);                                     \
        float n_ = ftanh(xn##SL + r_ * (hn + bn));                                 \
        h = fmaf(z_, h - n_, n_);                                                  \
        h_lds[lane] = h;                                                           \
        sum += h;                                                                  \
        mx = fmaxf(mx, h);                                                         \
        const float* rp_ = Pd + (size_t)tN_ * 192;                                 \
        asm volatile("global_load_dword %0, %1, off" : "=v"(xr##SL) : "v"(rp_ + lane));       \
        asm volatile("global_load_dword %0, %1, off" : "=v"(xz##SL) : "v"(rp_ + 64 + lane));  \
        asm volatile("global_load_dword %0, %1, off" : "=v"(xn##SL) : "v"(rp_ + 128 + lane)); \
        __builtin_amdgcn_sched_barrier(0);   /* region boundary: one step = one region */     \
    } while (0)

    for (int s = 0; s < TLEN; s += 4) {
        GRU_STEP(0, s + 0);
        GRU_STEP(1, s + 1);
        GRU_STEP(2, s + 2);
        GRU_STEP(3, s + 3);
    }
    asm volatile("s_waitcnt vmcnt(0)" ::: "memory");

    g_feats[b * 256 + dir * 64 + lane] = sum * (1.f / TLEN);
    g_feats[b * 256 + 128 + dir * 64 + lane] = mx;
#undef GRU_PRE
#undef GRU_STEP
#undef DOTK
}

// ---------------- Kernel C: classifier ----------------
__global__ __launch_bounds__(64) void classifier(
    const float* __restrict__ w1, const float* __restrict__ b1,
    const float* __restrict__ w2, const float* __restrict__ b2,
    float* __restrict__ out)
{
    const int b = blockIdx.x;
    const int i = threadIdx.x;
    __shared__ float f[256];
    __shared__ float hid[64];
    for (int c = i; c < 256; c += 64) f[c] = g_feats[b * 256 + c];
    __syncthreads();

    float acc = b1[i];
    const float* wrow = w1 + (size_t)i * 256;
#pragma unroll 16
    for (int c = 0; c < 256; c++) acc = fmaf(f[c], wrow[c], acc);
    hid[i] = acc * 0.5f * (1.f + erff(acc * 0.70710678118654752f));
    __syncthreads();

    if (i < NCLS) {
        float o = b2[i];
        const float* w2r = w2 + (size_t)i * 64;
#pragma unroll
        for (int j = 0; j < 64; j++) o = fmaf(hid[j], w2r[j], o);
        out[b * NCLS + i] = o;
    }
}

extern "C" void kernel_launch(void* const* d_in, const int* in_sizes, int n_in,
                              void* d_out, int out_size, void* d_ws, size_t ws_size,
                              hipStream_t stream) {
    const int*   tokens = (const int*)  d_in[0];
    const float* emb    = (const float*)d_in[1];
    const float* wih_f  = (const float*)d_in[2];
    const float* whh_f  = (const float*)d_in[3];
    const float* bih_f  = (const float*)d_in[4];
    const float* bhh_f  = (const float*)d_in[5];
    const float* wih_b  = (const float*)d_in[6];
    const float* whh_b  = (const float*)d_in[7];
    const float* bih_b  = (const float*)d_in[8];
    const float* bhh_b  = (const float*)d_in[9];
    const float* w1     = (const float*)d_in[10];
    const float* b1     = (const float*)d_in[11];
    const float* w2     = (const float*)d_in[12];
    const float* b2     = (const float*)d_in[13];
    float* out = (float*)d_out;

    precompute_P<<<4096, 384, 0, stream>>>(emb, wih_f, bih_f, wih_b, bih_b);
    gru_seq<<<2 * BATCH, 64, 0, stream>>>(tokens, whh_f, bhh_f, whh_b, bhh_b);
    classifier<<<BATCH, 64, 0, stream>>>(w1, b1, w2, b2, out);
}

// Round 12
// 951.313 us; speedup vs baseline: 7.3464x; 1.2107x over previous
//
#include <hip/hip_runtime.h>
#include <hip/hip_bf16.h>
#include <math.h>

#define VOCAB 50257
#define NCLS 20
#define EDIM 64
#define HDIM 64
#define BATCH 128
#define TLEN 2048

typedef float v2f __attribute__((ext_vector_type(2)));

// Static device scratch: no dependence on ws_size, graph-capture safe.
__device__ float g_P[(size_t)2 * VOCAB * 192];   // 77.2 MB, input-projected vocab table (bias folded)
__device__ float g_feats[BATCH * 256];           // pooled features

__device__ __forceinline__ float fast_rcp(float x) { return __builtin_amdgcn_rcpf(x); }

__device__ __forceinline__ float fsigmoid(float x) {
    return fast_rcp(1.f + __expf(-x));
}
__device__ __forceinline__ float ftanh(float x) {
    float e = __expf(2.f * x);
    return 1.f - 2.f * fast_rcp(e + 1.f);
}

// ---------------- Kernel A: P[dir][v][g] = dot(emb[v], wih[dir][g]) + bih[dir][g] ----------------
__global__ __launch_bounds__(384) void precompute_P(
    const float* __restrict__ emb,
    const float* __restrict__ wih_f, const float* __restrict__ bih_f,
    const float* __restrict__ wih_b, const float* __restrict__ bih_b)
{
    const int t = threadIdx.x;
    const int dir = t / 192;
    const int g = t % 192;
    const float* wih = dir ? wih_b : wih_f;
    const float* bih = dir ? bih_b : bih_f;

    float w[64];
#pragma unroll
    for (int e = 0; e < 64; e += 4) {
        float4 v = *(const float4*)(wih + (size_t)g * 64 + e);
        w[e] = v.x; w[e + 1] = v.y; w[e + 2] = v.z; w[e + 3] = v.w;
    }
    const float bias = bih[g];
    float* Pd = g_P + (size_t)dir * VOCAB * 192;

    for (int v = blockIdx.x * 2; v < VOCAB; v += gridDim.x * 2) {
        const int v1ok = (v + 1 < VOCAB);
        const float4* e0 = (const float4*)(emb + (size_t)v * 64);
        const float4* e1 = (const float4*)(emb + (size_t)(v1ok ? v + 1 : v) * 64);
        float a0 = bias, a1 = bias;
#pragma unroll
        for (int e4 = 0; e4 < 16; e4++) {
            float4 x = e0[e4];
            float4 y = e1[e4];
            a0 = fmaf(x.x, w[4 * e4 + 0], a0);
            a1 = fmaf(y.x, w[4 * e4 + 0], a1);
            a0 = fmaf(x.y, w[4 * e4 + 1], a0);
            a1 = fmaf(y.y, w[4 * e4 + 1], a1);
            a0 = fmaf(x.z, w[4 * e4 + 2], a0);
            a1 = fmaf(y.z, w[4 * e4 + 2], a1);
            a0 = fmaf(x.w, w[4 * e4 + 3], a0);
            a1 = fmaf(y.w, w[4 * e4 + 3], a1);
        }
        Pd[(size_t)v * 192 + g] = a0;
        if (v1ok) Pd[(size_t)(v + 1) * 192 + g] = a1;
    }
}

// ---------------- Kernel B: one wave per (dir,batch); source-pipelined LDS reads ----------------
// R4 structure (verified 822us, absmax 0.0) with ONE change: the 16 h-broadcast
// ds_read_b128 are software-pipelined IN SOURCE ORDER (issue read k+4 before consuming
// read k, named H registers). Unlike R11's SGB+sched_barrier attempt (which regressed by
// walling off cross-step overlap), this leaves the scheduler fully free: it just hands it
// a dependence structure where reads stream 4 ahead of their FMA consumers, so the
// compiler's fine-grained lgkmcnt waits cover ~4 reads instead of draining the stream.
// FMA accumulation order is BIT-IDENTICAL to the verified kernel.
__global__ __launch_bounds__(64, 1) __attribute__((amdgpu_waves_per_eu(1, 1)))
void gru_seq(
    const int* __restrict__ tokens,
    const float* __restrict__ whh_f, const float* __restrict__ bhh_f,
    const float* __restrict__ whh_b, const float* __restrict__ bhh_b)
{
    const int lane = threadIdx.x;
    const int blk = blockIdx.x;
    const int b = blk >> 1;
    const int dir = blk & 1;
    const float* whh = dir ? whh_b : whh_f;
    const float* bhh = dir ? bhh_b : bhh_f;
    const float* Pd = g_P + (size_t)dir * VOCAB * 192;

    __shared__ __align__(16) float h_lds[64];
    __shared__ __align__(16) int tok_lds[TLEN];

    {
        const int4* src = (const int4*)(tokens + (size_t)b * TLEN);
        int4* dst = (int4*)tok_lds;
        for (int t = lane; t < TLEN / 4; t += 64) dst[t] = src[t];
    }

    v2f wr[32], wz[32], wn[32];
    {
        const float* pr = whh + (size_t)(0 + lane) * 64;
        const float* pz = whh + (size_t)(64 + lane) * 64;
        const float* pn = whh + (size_t)(128 + lane) * 64;
#pragma unroll
        for (int k = 0; k < 16; k++) {
            float4 a = *(const float4*)(pr + 4 * k);
            wr[2 * k] = (v2f){a.x, a.y}; wr[2 * k + 1] = (v2f){a.z, a.w};
            float4 c = *(const float4*)(pz + 4 * k);
            wz[2 * k] = (v2f){c.x, c.y}; wz[2 * k + 1] = (v2f){c.z, c.w};
            float4 d = *(const float4*)(pn + 4 * k);
            wn[2 * k] = (v2f){d.x, d.y}; wn[2 * k + 1] = (v2f){d.z, d.w};
        }
    }
    const float br = bhh[lane], bz = bhh[64 + lane], bn = bhh[128 + lane];

    h_lds[lane] = 0.f;
    float h = 0.f, sum = 0.f, mx = -INFINITY;

    auto tok_at = [&](int s) -> int {
        int ss = s < TLEN ? s : TLEN - 1;
        return tok_lds[dir ? (TLEN - 1 - ss) : ss];
    };

    float xr0, xz0, xn0, xr1, xz1, xn1, xr2, xz2, xn2, xr3, xz3, xn3;

#define GRU_PRE(SL, D) do {                                                        \
        const float* rd_ = Pd + (size_t)tok_at(D) * 192;                           \
        asm volatile("global_load_dword %0, %1, off" : "=v"(xr##SL) : "v"(rd_ + lane));       \
        asm volatile("global_load_dword %0, %1, off" : "=v"(xz##SL) : "v"(rd_ + 64 + lane));  \
        asm volatile("global_load_dword %0, %1, off" : "=v"(xn##SL) : "v"(rd_ + 128 + lane)); \
    } while (0)

    GRU_PRE(0, 0); GRU_PRE(1, 1); GRU_PRE(2, 2); GRU_PRE(3, 3);

    // one k-slice of the dot, consuming pre-loaded H register; order identical to R4
#define DOTQ(HK, K)                                                                \
        { v2f h01 = {HK.x, HK.y}, h23 = {HK.z, HK.w};                              \
          ar0 = __builtin_elementwise_fma(h01, wr[2 * K], ar0);                    \
          az0 = __builtin_elementwise_fma(h01, wz[2 * K], az0);                    \
          an0 = __builtin_elementwise_fma(h01, wn[2 * K], an0);                    \
          ar1 = __builtin_elementwise_fma(h23, wr[2 * K + 1], ar1);                \
          az1 = __builtin_elementwise_fma(h23, wz[2 * K + 1], az1);                \
          an1 = __builtin_elementwise_fma(h23, wn[2 * K + 1], an1); }

#define GRU_STEP(SL, SB) do {                                                      \
        const int tN_ = tok_at((SB) + 4);                                          \
        /* prime a 4-deep read pipeline */                                         \
        float4 H0 = *(const float4*)(h_lds + 0);                                   \
        float4 H1 = *(const float4*)(h_lds + 4);                                   \
        float4 H2 = *(const float4*)(h_lds + 8);                                   \
        float4 H3 = *(const float4*)(h_lds + 12);                                  \
        v2f ar0 = {0.f, 0.f}, ar1 = {0.f, 0.f};                                    \
        v2f az0 = {0.f, 0.f}, az1 = {0.f, 0.f};                                    \
        v2f an0 = {0.f, 0.f}, an1 = {0.f, 0.f};                                    \
        /* issue read k+4 before consuming read k */                               \
        float4 H4  = *(const float4*)(h_lds + 16);  DOTQ(H0, 0)                    \
        float4 H5  = *(const float4*)(h_lds + 20);  DOTQ(H1, 1)                    \
        float4 H6  = *(const float4*)(h_lds + 24);  DOTQ(H2, 2)                    \
        float4 H7  = *(const float4*)(h_lds + 28);  DOTQ(H3, 3)                    \
        float4 H8  = *(const float4*)(h_lds + 32);  DOTQ(H4, 4)                    \
        float4 H9  = *(const float4*)(h_lds + 36);  DOTQ(H5, 5)                    \
        float4 H10 = *(const float4*)(h_lds + 40);  DOTQ(H6, 6)                    \
        float4 H11 = *(const float4*)(h_lds + 44);  DOTQ(H7, 7)                    \
        float4 H12 = *(const float4*)(h_lds + 48);  DOTQ(H8, 8)                    \
        float4 H13 = *(const float4*)(h_lds + 52);  DOTQ(H9, 9)                    \
        float4 H14 = *(const float4*)(h_lds + 56);  DOTQ(H10, 10)                  \
        float4 H15 = *(const float4*)(h_lds + 60);  DOTQ(H11, 11)                  \
        DOTQ(H12, 12)                                                              \
        DOTQ(H13, 13)                                                              \
        DOTQ(H14, 14)                                                              \
        DOTQ(H15, 15)                                                              \
        float hr = (ar0.x + ar0.y) + (ar1.x + ar1.y);                              \
        float hz = (az0.x + az0.y) + (az1.x + az1.y);                              \
        float hn = (an0.x + an0.y) + (an1.x + an1.y);                              \
        asm volatile("s_waitcnt vmcnt(9)"                                          \
                     : "+v"(xr##SL), "+v"(xz##SL), "+v"(xn##SL));                  \
        float r_ = fsigmoid(xr##SL + hr + br);                                     \
        float z_ = fsigmoid(xz##SL + hz + bz);                                     \
        float n_ = ftanh(xn##SL + r_ * (hn + bn));                                 \
        h = fmaf(z_, h - n_, n_);                                                  \
        sum += h;                                                                  \
        mx = fmaxf(mx, h);                                                         \
        h_lds[lane] = h;                                                           \
        const float* rp_ = Pd + (size_t)tN_ * 192;                                 \
        asm volatile("global_load_dword %0, %1, off" : "=v"(xr##SL) : "v"(rp_ + lane));       \
        asm volatile("global_load_dword %0, %1, off" : "=v"(xz##SL) : "v"(rp_ + 64 + lane));  \
        asm volatile("global_load_dword %0, %1, off" : "=v"(xn##SL) : "v"(rp_ + 128 + lane)); \
    } while (0)

    for (int s = 0; s < TLEN; s += 4) {
        GRU_STEP(0, s + 0);
        GRU_STEP(1, s + 1);
        GRU_STEP(2, s + 2);
        GRU_STEP(3, s + 3);
    }
    asm volatile("s_waitcnt vmcnt(0)" ::: "memory");

    g_feats[b * 256 + dir * 64 + lane] = sum * (1.f / TLEN);
    g_feats[b * 256 + 128 + dir * 64 + lane] = mx;
#undef GRU_PRE
#undef GRU_STEP
#undef DOTQ
}

// ---------------- Kernel C: classifier ----------------
__global__ __launch_bounds__(64) void classifier(
    const float* __restrict__ w1, const float* __restrict__ b1,
    const float* __restrict__ w2, const float* __restrict__ b2,
    float* __restrict__ out)
{
    const int b = blockIdx.x;
    const int i = threadIdx.x;
    __shared__ float f[256];
    __shared__ float hid[64];
    for (int c = i; c < 256; c += 64) f[c] = g_feats[b * 256 + c];
    __syncthreads();

    float acc = b1[i];
    const float* wrow = w1 + (size_t)i * 256;
#pragma unroll 16
    for (int c = 0; c < 256; c++) acc = fmaf(f[c], wrow[c], acc);
    hid[i] = acc * 0.5f * (1.f + erff(acc * 0.70710678118654752f));
    __syncthreads();

    if (i < NCLS) {
        float o = b2[i];
        const float* w2r = w2 + (size_t)i * 64;
#pragma unroll
        for (int j = 0; j < 64; j++) o = fmaf(hid[j], w2r[j], o);
        out[b * NCLS + i] = o;
    }
}

extern "C" void kernel_launch(void* const* d_in, const int* in_sizes, int n_in,
                              void* d_out, int out_size, void* d_ws, size_t ws_size,
                              hipStream_t stream) {
    const int*   tokens = (const int*)  d_in[0];
    const float* emb    = (const float*)d_in[1];
    const float* wih_f  = (const float*)d_in[2];
    const float* whh_f  = (const float*)d_in[3];
    const float* bih_f  = (const float*)d_in[4];
    const float* bhh_f  = (const float*)d_in[5];
    const float* wih_b  = (const float*)d_in[6];
    const float* whh_b  = (const float*)d_in[7];
    const float* bih_b  = (const float*)d_in[8];
    const float* bhh_b  = (const float*)d_in[9];
    const float* w1     = (const float*)d_in[10];
    const float* b1     = (const float*)d_in[11];
    const float* w2     = (const float*)d_in[12];
    const float* b2     = (const float*)d_in[13];
    float* out = (float*)d_out;

    precompute_P<<<4096, 384, 0, stream>>>(emb, wih_f, bih_f, wih_b, bih_b);
    gru_seq<<<2 * BATCH, 64, 0, stream>>>(tokens, whh_f, bhh_f, whh_b, bhh_b);
    classifier<<<BATCH, 64, 0, stream>>>(w1, b1, w2, b2, out);
}